// Round 1
// baseline (441.239 us; speedup 1.0000x reference)
//
#include <hip/hip_runtime.h>
#include <math.h>

// ---------------- problem constants ----------------
#define N_   32
#define NUP_ 16
#define M_   4
#define D_   128
#define K_   64
#define F_   32
#define H_   45
#define L_   3
#define LOG2_ 0.69314718055994530942f

typedef __attribute__((ext_vector_type(8))) short short8;
typedef __attribute__((ext_vector_type(4))) float float4v;

__device__ __forceinline__ float ssp(float v) {
    // softplus(v) - log(2) == log(0.5 + 0.5*e^v); ssp(0) == 0 exactly
    return __logf(fmaf(0.5f, __expf(v), 0.5f));
}

__device__ __forceinline__ unsigned short f2bf(float x) {   // RTNE, prep only
    unsigned int u = __float_as_uint(x);
    return (unsigned short)((u + 0x7FFFu + ((u >> 16) & 1u)) >> 16);
}

// pack two floats -> bf16x2 in ONE VALU op (RTNE)
__device__ __forceinline__ unsigned int cvtpk(float x, float y) {
    unsigned int r;
    asm("v_cvt_pk_bf16_f32 %0, %1, %2" : "=v"(r) : "v"(x), "v"(y));
    return r;
}

// ---------------- prep: pack all weights into MFMA B-fragment order ----------------
// w1B[lc][nt:3][512]   B-frag: k=(lane>>4)*8+jj (f), n=nt*16+(lane&15) (hidden, id map)
// w2B[lc][ks:2][nt:4][512]  k=p (hidden position), n=kout. pos p: u=(p&3)*16+(p>>2) if p&3<3;
//                            p==3 -> bias row (pairs with hd[row][3]=1.0); else 0
// gB [l][ks:6][nt:8][512]   k=c*64+kk, n=d
// hB [li:2][ks:4][nt2:4][512] k=p, d=(p&7)*16+(p>>3), n=kout   (hW layers 1,2)
// gbs[l][128] = sum_c gb[l][c][:]
__global__ __launch_bounds__(256) void prep_kernel(
    const float* __restrict__ wW1, const float* __restrict__ wb2_unused,
    const float* __restrict__ wW2, const float* __restrict__ wb2,
    const float* __restrict__ gW,  const float* __restrict__ hW,
    const float* __restrict__ gb,
    short* __restrict__ w1B, short* __restrict__ w2B,
    short* __restrict__ gB,  short* __restrict__ hB, float* __restrict__ gbs)
{
    int blk = blockIdx.x;
    int t = threadIdx.x;
    if (blk < 27) {                       // w1B
        int lc = blk / 3, nt = blk % 3;
        short* dst = w1B + (size_t)blk * 512;
        for (int idx = t; idx < 512; idx += 256) {
            int lane = idx >> 3, jj = idx & 7;
            int k = ((lane >> 4) << 3) + jj;
            int n = nt * 16 + (lane & 15);
            float v = (n < H_) ? wW1[((size_t)lc * H_ + n) * F_ + k] : 0.0f;
            dst[idx] = (short)f2bf(v);
        }
    } else if (blk < 99) {                // w2B
        int b3 = blk - 27;
        int lc = b3 >> 3, rem = b3 & 7, ks = rem >> 2, nt = rem & 3;
        short* dst = w2B + (size_t)b3 * 512;
        for (int idx = t; idx < 512; idx += 256) {
            int lane = idx >> 3, jj = idx & 7;
            int p = ks * 32 + ((lane >> 4) << 3) + jj;
            int n = nt * 16 + (lane & 15);
            float v;
            if (p == 3) v = wb2[(size_t)lc * K_ + n];
            else if ((p & 3) < 3) {
                int u = (p & 3) * 16 + (p >> 2);
                v = (u < H_) ? wW2[((size_t)lc * K_ + n) * H_ + u] : 0.0f;
            } else v = 0.0f;
            dst[idx] = (short)f2bf(v);
        }
    } else if (blk < 243) {               // gB
        int g = blk - 99;
        int l = g / 48, rem = g % 48;     // rem = ks*8+nt
        short* dst = gB + (size_t)g * 512;
        for (int idx = t; idx < 512; idx += 256) {
            int lane = idx >> 3, jj = idx & 7;
            int k = (rem >> 3) * 32 + ((lane >> 4) << 3) + jj;  // 0..191
            int c = k >> 6, kk = k & 63;
            int n = ((rem & 7) * 16) + (lane & 15);
            dst[idx] = (short)f2bf(gW[(((size_t)l * 3 + c) * D_ + n) * K_ + kk]);
        }
    } else if (blk < 275) {               // hB
        int hh = blk - 243;
        int li = hh >> 4, rem = hh & 15;  // rem = ks*4+nt2
        short* dst = hB + (size_t)hh * 512;
        for (int idx = t; idx < 512; idx += 256) {
            int lane = idx >> 3, jj = idx & 7;
            int p = (rem >> 2) * 32 + ((lane >> 4) << 3) + jj;  // 0..127
            int d = (p & 7) * 16 + (p >> 3);
            int n = ((rem & 3) * 16) + (lane & 15);
            dst[idx] = (short)f2bf(hW[(((size_t)(li + 1)) * K_ + n) * D_ + d]);
        }
    } else {                              // gbs
        for (int idx = t; idx < 384; idx += 256) {
            int l = idx >> 7, d = idx & 127;
            gbs[idx] = gb[((size_t)l * 3 + 0) * D_ + d]
                     + gb[((size_t)l * 3 + 1) * D_ + d]
                     + gb[((size_t)l * 3 + 2) * D_ + d];
        }
    }
}

// ---------------- h0: layer-0 h is a single broadcast row ----------------
__global__ __launch_bounds__(64) void h0_kernel(
    const float* __restrict__ X, const float* __restrict__ hW,
    const float* __restrict__ hb, float* __restrict__ h0)
{
    int k = threadIdx.x;
    float a = hb[k];
    const float* w = hW + (size_t)k * D_;
    #pragma unroll 8
    for (int dd = 0; dd < D_; ++dd) a += w[dd] * X[dd];
    h0[k] = a;
}

// ---------------- MFMA edge kernel: 4 waves/WG, one (b,i) per wave ----------------
#define WSTRIDE 68     // f32 words per wrow row
#define HDS 72         // shorts per hd row (16B-aligned stride, bank-spread)
__global__ __launch_bounds__(256, 8) void edge_kernel(
    const float* __restrict__ ee, const float* __restrict__ en,
    const float* __restrict__ Y,
    const short* __restrict__ w1B, const float* __restrict__ wb1,
    const short* __restrict__ w2B,
    const float* __restrict__ h, const float* __restrict__ h0,
    unsigned short* __restrict__ zb, int l, int hmode)
{
    __shared__ float wrow[36 * WSTRIDE];          // 9792 B (h rows 0..31, Y rows 32..35)
    __shared__ short hd_s[4][16 * HDS];           // 9216 B

    const int tid  = threadIdx.x;
    const int wv   = tid >> 6;
    const int lane = tid & 63;
    const int quad = lane >> 4;
    const int l16  = lane & 15;
    const int b    = blockIdx.x >> 3;
    const int i    = ((blockIdx.x & 7) << 2) + wv;
    const int bi   = (b << 5) + i;

    // ---- stage wrow cooperatively ----
    {
        int row = tid >> 3;
        int col = (tid & 7) * 8;
        const float* src = hmode ? (h + ((size_t)(b * N_ + row)) * K_ + col) : (h0 + col);
        float4 v0 = *(const float4*)(src);
        float4 v1 = *(const float4*)(src + 4);
        *(float4*)(wrow + row * WSTRIDE + col)     = v0;
        *(float4*)(wrow + row * WSTRIDE + col + 4) = v1;
        if (tid < 32) {
            int r2 = tid >> 3, o2 = (tid & 7) * 8;
            float4 y0 = *(const float4*)(Y + (size_t)r2 * K_ + o2);
            float4 y1 = *(const float4*)(Y + (size_t)r2 * K_ + o2 + 4);
            *(float4*)(wrow + (32 + r2) * WSTRIDE + o2)     = y0;
            *(float4*)(wrow + (32 + r2) * WSTRIDE + o2 + 4) = y1;
        }
    }
    __syncthreads();

    const int cA = (i < NUP_) ? 0 : 1;
    short* hd = hd_s[wv];
    const float c3  = (l16 == 0) ? 1.0f : 0.0f;   // 1.0 in bias slot (pos 3)
    const int   ri  = i & 3;                      // dead r within dead quad (t<2)
    const int   tqi = (i & 15) >> 2;              // dead quad (t<2)
    const int   tti = i >> 4;                     // tile holding self-row

    #pragma unroll
    for (int t = 0; t < 3; ++t) {
        const int c  = (t == 2) ? 2 : ((t == 0) ? cA : 1 - cA);
        const int lc = l * 3 + c;

        // ---- A-frag: 8 consecutive f of this lane's edge row, straight from global ----
        float4 fa = {0.f, 0.f, 0.f, 0.f}, fb = {0.f, 0.f, 0.f, 0.f};
        if (t < 2) {
            const float* ep = ee + (((size_t)bi * N_) + t * 16 + l16) * F_ + quad * 8;
            fa = *(const float4*)(ep);
            fb = *(const float4*)(ep + 4);
        } else if (l16 < M_) {
            const float* np = en + (((size_t)bi * M_) + l16) * F_ + quad * 8;
            fa = *(const float4*)(np);
            fb = *(const float4*)(np + 4);
        }
        union { short8 s; unsigned int u[4]; } A;
        A.u[0] = cvtpk(fa.x, fa.y); A.u[1] = cvtpk(fa.z, fa.w);
        A.u[2] = cvtpk(fb.x, fb.y); A.u[3] = cvtpk(fb.z, fb.w);

        // ---- stage 1: one K-step, 3 column tiles ----
        float4v acc1[3];
        #pragma unroll
        for (int nt = 0; nt < 3; ++nt) {
            int col = nt * 16 + l16;
            float b1c = (col < H_) ? wb1[(size_t)lc * H_ + col] : 0.0f;
            acc1[nt] = (float4v){b1c, b1c, b1c, b1c};
            short8 bf = *(const short8*)(w1B + (((size_t)lc * 3 + nt) << 9) + (lane << 3));
            acc1[nt] = __builtin_amdgcn_mfma_f32_16x16x32_bf16(A.s, bf, acc1[nt], 0, 0, 0);
        }

        // ---- ssp + packed b64 hidden write; dead rows (self-row / t2 rows>=4)
        //      are zeroed HERE (incl. bias slot) so the epilogue needs no mask ----
        const bool deadq = (t < 2) ? ((tti == t) && (quad == tqi)) : (quad != 0);
        #pragma unroll
        for (int r = 0; r < 4; ++r) {
            float s0 = ssp(acc1[0][r]);
            float s1 = ssp(acc1[1][r]);
            float s2 = ssp(acc1[2][r]);
            uint2 pr;
            pr.x = cvtpk(s0, s1);
            pr.y = cvtpk(s2, c3);
            const bool dead = deadq && ((t == 2) || (r == ri));
            if (dead) { pr.x = 0u; pr.y = 0u; }
            *(uint2*)(hd + (quad * 4 + r) * HDS + 4 * l16) = pr;
        }

        // ---- stage 2: two K-steps, bias via k=3 slot ----
        float4v acc2[4];
        #pragma unroll
        for (int nt = 0; nt < 4; ++nt) acc2[nt] = (float4v){0.f, 0.f, 0.f, 0.f};
        #pragma unroll
        for (int ks = 0; ks < 2; ++ks) {
            short8 a2 = *(const short8*)(hd + l16 * HDS + ks * 32 + quad * 8);
            #pragma unroll
            for (int nt = 0; nt < 4; ++nt) {
                short8 bf = *(const short8*)(w2B + ((((size_t)lc * 2 + ks) * 4 + nt) << 9) + (lane << 3));
                acc2[nt] = __builtin_amdgcn_mfma_f32_16x16x32_bf16(a2, bf, acc2[nt], 0, 0, 0);
            }
        }

        // ---- epilogue: msg * h(j,k), sum over rows — UNMASKED (dead rows are 0) ----
        // t==2: only quad 0 rows are live; all quads read rows 32+r (broadcast, in
        // bounds, finite) and dead quads contribute exact 0 via zeroed acc2.
        float p0 = 0.f, p1 = 0.f, p2 = 0.f, p3 = 0.f;
        #pragma unroll
        for (int r = 0; r < 4; ++r) {
            const int jrow = (t == 2) ? (32 + r) : (t * 16 + quad * 4 + r);
            const float* wr = wrow + jrow * WSTRIDE + l16;
            p0 += acc2[0][r] * wr[0];
            p1 += acc2[1][r] * wr[16];
            p2 += acc2[2][r] * wr[32];
            p3 += acc2[3][r] * wr[48];
        }

        // ---- butterfly reduce with value swap: 3 shuffles, no final select ----
        const bool qlo = (quad & 1) != 0;
        const bool qhi = (quad & 2) != 0;
        float u  = qlo ? p1 : p0;
        float us = qlo ? p0 : p1;
        u += __shfl_xor(u * 0.0f + us, 16);   // keep compiler from merging selects
        float w  = qlo ? p3 : p2;
        float ws = qlo ? p2 : p3;
        w += __shfl_xor(ws, 16);
        float v  = qhi ? w : u;
        float vs = qhi ? u : w;
        v += __shfl_xor(vs, 32);

        unsigned int pk = cvtpk(v, v);
        zb[(size_t)bi * 192 + c * 64 + lane] = (unsigned short)pk;
    }
}

// ---------------- MFMA fuse: x += Z@Gcat^T + gbs; h_next = x@hW^T + hb ----------------
#define HXS 136   // shorts per hx row
__global__ __launch_bounds__(256) void fuse_kernel(
    const unsigned short* __restrict__ zb, const short* __restrict__ gB,
    const float* __restrict__ gbs, const float* __restrict__ X,
    const short* __restrict__ hB, const float* __restrict__ hb,
    float* __restrict__ xout, float* __restrict__ hout,
    int l, int first, int compute_h)
{
    __shared__ short hx_s[4][16 * HXS];    // 17408 B

    const int tid  = threadIdx.x;
    const int wv   = tid >> 6;
    const int lane = tid & 63;
    const int quad = lane >> 4;
    const int l16  = lane & 15;
    const int bi0  = (blockIdx.x * 4 + wv) * 16;

    // ---- Z @ Gcat^T : 6 K-steps x 8 column tiles ----
    float4v ax[8];
    #pragma unroll
    for (int nt = 0; nt < 8; ++nt) ax[nt] = (float4v){0.f, 0.f, 0.f, 0.f};
    const short* gb_ = gB + (size_t)l * 48 * 512;
    const short* zrow = (const short*)zb + ((size_t)(bi0 + l16)) * 192;
    #pragma unroll
    for (int ks = 0; ks < 6; ++ks) {
        short8 az = *(const short8*)(zrow + ks * 32 + quad * 8);
        #pragma unroll
        for (int nt = 0; nt < 8; ++nt) {
            short8 bf = *(const short8*)(gb_ + (((size_t)ks * 8 + nt) << 9) + (lane << 3));
            ax[nt] = __builtin_amdgcn_mfma_f32_16x16x32_bf16(az, bf, ax[nt], 0, 0, 0);
        }
    }

    // ---- epilogue: residual + biases, store x, pack bf16 rows for h-GEMM ----
    float gv[8], xb[8];
    #pragma unroll
    for (int nt = 0; nt < 8; ++nt) {
        gv[nt] = gbs[(size_t)l * D_ + nt * 16 + l16];
        if (first) xb[nt] = X[nt * 16 + l16];
    }
    short* hx = hx_s[wv];
    #pragma unroll
    for (int r = 0; r < 4; ++r) {
        int row = quad * 4 + r;
        size_t gi = ((size_t)(bi0 + row)) * D_ + l16;
        float xv[8];
        #pragma unroll
        for (int nt = 0; nt < 8; ++nt) {
            float xo = (first ? xb[nt] : xout[gi + nt * 16]) + gv[nt] + ax[nt][r];
            xout[gi + nt * 16] = xo;
            xv[nt] = xo;
        }
        if (compute_h) {
            union { short8 s; unsigned int u[4]; } P;
            P.u[0] = cvtpk(xv[0], xv[1]); P.u[1] = cvtpk(xv[2], xv[3]);
            P.u[2] = cvtpk(xv[4], xv[5]); P.u[3] = cvtpk(xv[6], xv[7]);
            *(short8*)(hx + row * HXS + 8 * l16) = P.s;
        }
    }
    if (!compute_h) return;

    // ---- h_next = x @ hW^T : 4 K-steps x 4 column tiles ----
    float4v ah[4];
    #pragma unroll
    for (int nt = 0; nt < 4; ++nt) ah[nt] = (float4v){0.f, 0.f, 0.f, 0.f};
    const short* hb_ = hB + (size_t)l * 16 * 512;
    #pragma unroll
    for (int ks = 0; ks < 4; ++ks) {
        short8 a = *(const short8*)(hx + l16 * HXS + ks * 32 + quad * 8);
        #pragma unroll
        for (int nt = 0; nt < 4; ++nt) {
            short8 bf = *(const short8*)(hb_ + (((size_t)ks * 4 + nt) << 9) + (lane << 3));
            ah[nt] = __builtin_amdgcn_mfma_f32_16x16x32_bf16(a, bf, ah[nt], 0, 0, 0);
        }
    }
    float hbv[4];
    #pragma unroll
    for (int nt = 0; nt < 4; ++nt) hbv[nt] = hb[((size_t)(l + 1)) * K_ + nt * 16 + l16];
    #pragma unroll
    for (int nt = 0; nt < 4; ++nt)
        #pragma unroll
        for (int r = 0; r < 4; ++r)
            hout[((size_t)(bi0 + quad * 4 + r)) * K_ + nt * 16 + l16] = ah[nt][r] + hbv[nt];
}

// ---------------- launch ----------------
extern "C" void kernel_launch(void* const* d_in, const int* in_sizes, int n_in,
                              void* d_out, int out_size, void* d_ws, size_t ws_size,
                              hipStream_t stream)
{
    const float* ee  = (const float*)d_in[0];
    const float* en  = (const float*)d_in[1];
    const float* X   = (const float*)d_in[2];
    const float* Y   = (const float*)d_in[3];
    const float* wW1 = (const float*)d_in[4];
    const float* wb1 = (const float*)d_in[5];
    const float* wW2 = (const float*)d_in[6];
    const float* wb2 = (const float*)d_in[7];
    const float* hW  = (const float*)d_in[8];
    const float* hb  = (const float*)d_in[9];
    const float* gW  = (const float*)d_in[10];
    const float* gb  = (const float*)d_in[11];
    float* xout = (float*)d_out;

    // workspace carve (byte offsets, all 16B-aligned)
    char* ws = (char*)d_ws;
    float*          h   = (float*)(ws);                         // 8,388,608 B
    unsigned short* zb  = (unsigned short*)(ws + 8388608);      // 12,582,912 B
    float*          h0  = (float*)(ws + 8388608 + 12582912);    // 256 B
    short*          w1B = (short*)(ws + 20971520 + 256);        // 27,648 B
    short*          w2B = w1B + (size_t)27 * 512;               // 73,728 B
    short*          gB  = w2B + (size_t)72 * 512;               // 147,456 B
    short*          hB  = gB  + (size_t)144 * 512;              // 32,768 B
    float*          gbs = (float*)(hB + (size_t)32 * 512);      // 1,536 B

    prep_kernel<<<276, 256, 0, stream>>>(wW1, wb1, wW2, wb2, gW, hW, gb,
                                         w1B, w2B, gB, hB, gbs);
    h0_kernel<<<1, 64, 0, stream>>>(X, hW, hb, h0);

    // layer 0
    edge_kernel<<<8192, 256, 0, stream>>>(ee, en, Y, w1B, wb1, w2B, h, h0, zb, 0, 0);
    fuse_kernel<<<512, 256, 0, stream>>>(zb, gB, gbs, X, hB, hb, xout, h, 0, 1, 1);
    // layer 1
    edge_kernel<<<8192, 256, 0, stream>>>(ee, en, Y, w1B, wb1, w2B, h, h0, zb, 1, 1);
    fuse_kernel<<<512, 256, 0, stream>>>(zb, gB, gbs, X, hB, hb, xout, h, 1, 0, 1);
    // layer 2
    edge_kernel<<<8192, 256, 0, stream>>>(ee, en, Y, w1B, wb1, w2B, h, h0, zb, 2, 1);
    fuse_kernel<<<512, 256, 0, stream>>>(zb, gB, gbs, X, hB, hb, xout, h, 2, 0, 0);
}

// Round 3
// 400.430 us; speedup vs baseline: 1.1019x; 1.1019x over previous
//
#include <hip/hip_runtime.h>
#include <math.h>

// ---------------- problem constants ----------------
#define N_   32
#define NUP_ 16
#define M_   4
#define D_   128
#define K_   64
#define F_   32
#define H_   45
#define L_   3
#define LOG2_ 0.69314718055994530942f

typedef __attribute__((ext_vector_type(8))) short short8;
typedef __attribute__((ext_vector_type(4))) float float4v;

__device__ __forceinline__ float ssp(float v) {
    // softplus(v) - log(2) == log(0.5 + 0.5*e^v); ssp(0) == 0 exactly
    return __logf(fmaf(0.5f, __expf(v), 0.5f));
}

__device__ __forceinline__ unsigned short f2bf(float x) {   // RTNE, prep only
    unsigned int u = __float_as_uint(x);
    return (unsigned short)((u + 0x7FFFu + ((u >> 16) & 1u)) >> 16);
}

// pack two floats -> bf16x2 in ONE VALU op (RTNE)
__device__ __forceinline__ unsigned int cvtpk(float x, float y) {
    unsigned int r;
    asm("v_cvt_pk_bf16_f32 %0, %1, %2" : "=v"(r) : "v"(x), "v"(y));
    return r;
}

// ---------------- prep: pack all weights into MFMA B-fragment order ----------------
// w1B[lc][nt:3][512]   B-frag: k=(lane>>4)*8+jj (f), n=nt*16+(lane&15) (hidden, id map)
// w2B[lc][ks:2][nt:4][512]  k=p (hidden position), n=kout. pos p: u=(p&3)*16+(p>>2) if p&3<3;
//                            p==3 -> bias row (pairs with hd[row][3]=1.0); else 0
// gB [l][ks:6][nt:8][512]   k=c*64+kk, n=d
// hB [li:2][ks:4][nt2:4][512] k=p, d=(p&7)*16+(p>>3), n=kout   (hW layers 1,2)
// gbs[l][128] = sum_c gb[l][c][:]
__global__ __launch_bounds__(256) void prep_kernel(
    const float* __restrict__ wW1, const float* __restrict__ wb2_unused,
    const float* __restrict__ wW2, const float* __restrict__ wb2,
    const float* __restrict__ gW,  const float* __restrict__ hW,
    const float* __restrict__ gb,
    short* __restrict__ w1B, short* __restrict__ w2B,
    short* __restrict__ gB,  short* __restrict__ hB, float* __restrict__ gbs)
{
    int blk = blockIdx.x;
    int t = threadIdx.x;
    if (blk < 27) {                       // w1B
        int lc = blk / 3, nt = blk % 3;
        short* dst = w1B + (size_t)blk * 512;
        for (int idx = t; idx < 512; idx += 256) {
            int lane = idx >> 3, jj = idx & 7;
            int k = ((lane >> 4) << 3) + jj;
            int n = nt * 16 + (lane & 15);
            float v = (n < H_) ? wW1[((size_t)lc * H_ + n) * F_ + k] : 0.0f;
            dst[idx] = (short)f2bf(v);
        }
    } else if (blk < 99) {                // w2B
        int b3 = blk - 27;
        int lc = b3 >> 3, rem = b3 & 7, ks = rem >> 2, nt = rem & 3;
        short* dst = w2B + (size_t)b3 * 512;
        for (int idx = t; idx < 512; idx += 256) {
            int lane = idx >> 3, jj = idx & 7;
            int p = ks * 32 + ((lane >> 4) << 3) + jj;
            int n = nt * 16 + (lane & 15);
            float v;
            if (p == 3) v = wb2[(size_t)lc * K_ + n];
            else if ((p & 3) < 3) {
                int u = (p & 3) * 16 + (p >> 2);
                v = (u < H_) ? wW2[((size_t)lc * K_ + n) * H_ + u] : 0.0f;
            } else v = 0.0f;
            dst[idx] = (short)f2bf(v);
        }
    } else if (blk < 243) {               // gB
        int g = blk - 99;
        int l = g / 48, rem = g % 48;     // rem = ks*8+nt
        short* dst = gB + (size_t)g * 512;
        for (int idx = t; idx < 512; idx += 256) {
            int lane = idx >> 3, jj = idx & 7;
            int k = (rem >> 3) * 32 + ((lane >> 4) << 3) + jj;  // 0..191
            int c = k >> 6, kk = k & 63;
            int n = ((rem & 7) * 16) + (lane & 15);
            dst[idx] = (short)f2bf(gW[(((size_t)l * 3 + c) * D_ + n) * K_ + kk]);
        }
    } else if (blk < 275) {               // hB
        int hh = blk - 243;
        int li = hh >> 4, rem = hh & 15;  // rem = ks*4+nt2
        short* dst = hB + (size_t)hh * 512;
        for (int idx = t; idx < 512; idx += 256) {
            int lane = idx >> 3, jj = idx & 7;
            int p = (rem >> 2) * 32 + ((lane >> 4) << 3) + jj;  // 0..127
            int d = (p & 7) * 16 + (p >> 3);
            int n = ((rem & 3) * 16) + (lane & 15);
            dst[idx] = (short)f2bf(hW[(((size_t)(li + 1)) * K_ + n) * D_ + d]);
        }
    } else {                              // gbs
        for (int idx = t; idx < 384; idx += 256) {
            int l = idx >> 7, d = idx & 127;
            gbs[idx] = gb[((size_t)l * 3 + 0) * D_ + d]
                     + gb[((size_t)l * 3 + 1) * D_ + d]
                     + gb[((size_t)l * 3 + 2) * D_ + d];
        }
    }
}

// ---------------- h0: layer-0 h is a single broadcast row ----------------
__global__ __launch_bounds__(64) void h0_kernel(
    const float* __restrict__ X, const float* __restrict__ hW,
    const float* __restrict__ hb, float* __restrict__ h0)
{
    int k = threadIdx.x;
    float a = hb[k];
    const float* w = hW + (size_t)k * D_;
    #pragma unroll 8
    for (int dd = 0; dd < D_; ++dd) a += w[dd] * X[dd];
    h0[k] = a;
}

// ---------------- MFMA edge kernel: 4 waves/WG, one (b,i) per wave ----------------
// Elec tiles t=0,1: per-wave. Nuclear tile: the block's 4 i's contribute 4 live
// rows each (row = 4*local_i + m) -> ONE 16-row MFMA tile handled by wave 0 only.
#define WSTRIDE 68     // f32 words per wrow row
#define HDS 72         // shorts per hd row (16B-aligned stride, bank-spread)
__global__ __launch_bounds__(256, 8) void edge_kernel(
    const float* __restrict__ ee, const float* __restrict__ en,
    const float* __restrict__ Y,
    const short* __restrict__ w1B, const float* __restrict__ wb1,
    const short* __restrict__ w2B,
    const float* __restrict__ h, const float* __restrict__ h0,
    unsigned short* __restrict__ zb, int l, int hmode)
{
    __shared__ float wrow[36 * WSTRIDE];          // 9792 B (h rows 0..31, Y rows 32..35)
    __shared__ short hd_s[4][16 * HDS];           // 9216 B

    const int tid  = threadIdx.x;
    const int wv   = tid >> 6;
    const int lane = tid & 63;
    const int quad = lane >> 4;
    const int l16  = lane & 15;
    const int b    = blockIdx.x >> 3;
    const int i    = ((blockIdx.x & 7) << 2) + wv;
    const int bi   = (b << 5) + i;

    // ---- stage wrow cooperatively ----
    {
        int row = tid >> 3;
        int col = (tid & 7) * 8;
        const float* src = hmode ? (h + ((size_t)(b * N_ + row)) * K_ + col) : (h0 + col);
        float4 v0 = *(const float4*)(src);
        float4 v1 = *(const float4*)(src + 4);
        *(float4*)(wrow + row * WSTRIDE + col)     = v0;
        *(float4*)(wrow + row * WSTRIDE + col + 4) = v1;
        if (tid < 32) {
            int r2 = tid >> 3, o2 = (tid & 7) * 8;
            float4 y0 = *(const float4*)(Y + (size_t)r2 * K_ + o2);
            float4 y1 = *(const float4*)(Y + (size_t)r2 * K_ + o2 + 4);
            *(float4*)(wrow + (32 + r2) * WSTRIDE + o2)     = y0;
            *(float4*)(wrow + (32 + r2) * WSTRIDE + o2 + 4) = y1;
        }
    }
    __syncthreads();

    const int cA = (i < NUP_) ? 0 : 1;
    short* hd = hd_s[wv];
    const float c3  = (l16 == 0) ? 1.0f : 0.0f;   // 1.0 in bias slot (pos 3)
    const int   ri  = i & 3;                      // dead r within dead quad
    const int   tqi = (i & 15) >> 2;              // dead quad
    const int   tti = i >> 4;                     // tile holding self-row

    // ================= electron tiles =================
    #pragma unroll
    for (int t = 0; t < 2; ++t) {
        const int c  = (t == 0) ? cA : 1 - cA;
        const int lc = l * 3 + c;

        // ---- A-frag: 8 consecutive f of this lane's edge row ----
        const float* ep = ee + (((size_t)bi * N_) + t * 16 + l16) * F_ + quad * 8;
        float4 fa = *(const float4*)(ep);
        float4 fb = *(const float4*)(ep + 4);
        union { short8 s; unsigned int u[4]; } A;
        A.u[0] = cvtpk(fa.x, fa.y); A.u[1] = cvtpk(fa.z, fa.w);
        A.u[2] = cvtpk(fb.x, fb.y); A.u[3] = cvtpk(fb.z, fb.w);

        // ---- stage 1: one K-step, 3 column tiles ----
        float4v acc1[3];
        #pragma unroll
        for (int nt = 0; nt < 3; ++nt) {
            int col = nt * 16 + l16;
            float b1c = (col < H_) ? wb1[(size_t)lc * H_ + col] : 0.0f;
            acc1[nt] = (float4v){b1c, b1c, b1c, b1c};
            short8 bf = *(const short8*)(w1B + (((size_t)lc * 3 + nt) << 9) + (lane << 3));
            acc1[nt] = __builtin_amdgcn_mfma_f32_16x16x32_bf16(A.s, bf, acc1[nt], 0, 0, 0);
        }

        // ---- ssp + packed b64 hidden write; self-row zeroed at the source ----
        const bool deadq = (tti == t) && (quad == tqi);
        #pragma unroll
        for (int r = 0; r < 4; ++r) {
            float s0 = ssp(acc1[0][r]);
            float s1 = ssp(acc1[1][r]);
            float s2 = ssp(acc1[2][r]);
            uint2 pr;
            pr.x = cvtpk(s0, s1);
            pr.y = cvtpk(s2, c3);
            if (deadq && (r == ri)) { pr.x = 0u; pr.y = 0u; }
            *(uint2*)(hd + (quad * 4 + r) * HDS + 4 * l16) = pr;
        }

        // ---- stage 2: two K-steps, bias via k=3 slot ----
        float4v acc2[4];
        #pragma unroll
        for (int nt = 0; nt < 4; ++nt) acc2[nt] = (float4v){0.f, 0.f, 0.f, 0.f};
        #pragma unroll
        for (int ks = 0; ks < 2; ++ks) {
            short8 a2 = *(const short8*)(hd + l16 * HDS + ks * 32 + quad * 8);
            #pragma unroll
            for (int nt = 0; nt < 4; ++nt) {
                short8 bf = *(const short8*)(w2B + ((((size_t)lc * 2 + ks) * 4 + nt) << 9) + (lane << 3));
                acc2[nt] = __builtin_amdgcn_mfma_f32_16x16x32_bf16(a2, bf, acc2[nt], 0, 0, 0);
            }
        }

        // ---- epilogue: msg * h(j,k), sum over rows — unmasked (dead row is 0) ----
        float p0 = 0.f, p1 = 0.f, p2 = 0.f, p3 = 0.f;
        #pragma unroll
        for (int r = 0; r < 4; ++r) {
            const int jrow = t * 16 + quad * 4 + r;
            const float* wr = wrow + jrow * WSTRIDE + l16;
            p0 += acc2[0][r] * wr[0];
            p1 += acc2[1][r] * wr[16];
            p2 += acc2[2][r] * wr[32];
            p3 += acc2[3][r] * wr[48];
        }

        // ---- butterfly reduce with value swap: 3 shuffles, no final select ----
        const bool qlo = (quad & 1) != 0;
        const bool qhi = (quad & 2) != 0;
        float u  = qlo ? p1 : p0;
        float us = qlo ? p0 : p1;
        u += __shfl_xor(us, 16);
        float w  = qlo ? p3 : p2;
        float ws = qlo ? p2 : p3;
        w += __shfl_xor(ws, 16);
        float v  = qhi ? w : u;
        float vs = qhi ? u : w;
        v += __shfl_xor(vs, 32);

        zb[(size_t)bi * 192 + c * 64 + lane] = (unsigned short)cvtpk(v, v);
    }

    // ================= nuclear tile: wave 0 only, 4 i's x 4 m's =================
    if (wv == 0) {
        const int lc = l * 3 + 2;

        // row = 4*local_i + m == l16; en[((b*32+base)+li)*4 + m] == en[bi*4 + l16]
        const float* np = en + ((size_t)bi * M_ + l16) * F_ + quad * 8;
        float4 fa = *(const float4*)(np);
        float4 fb = *(const float4*)(np + 4);
        union { short8 s; unsigned int u[4]; } A;
        A.u[0] = cvtpk(fa.x, fa.y); A.u[1] = cvtpk(fa.z, fa.w);
        A.u[2] = cvtpk(fb.x, fb.y); A.u[3] = cvtpk(fb.z, fb.w);

        float4v acc1[3];
        #pragma unroll
        for (int nt = 0; nt < 3; ++nt) {
            int col = nt * 16 + l16;
            float b1c = (col < H_) ? wb1[(size_t)lc * H_ + col] : 0.0f;
            acc1[nt] = (float4v){b1c, b1c, b1c, b1c};
            short8 bf = *(const short8*)(w1B + (((size_t)lc * 3 + nt) << 9) + (lane << 3));
            acc1[nt] = __builtin_amdgcn_mfma_f32_16x16x32_bf16(A.s, bf, acc1[nt], 0, 0, 0);
        }

        #pragma unroll
        for (int r = 0; r < 4; ++r) {   // all 16 rows live
            float s0 = ssp(acc1[0][r]);
            float s1 = ssp(acc1[1][r]);
            float s2 = ssp(acc1[2][r]);
            uint2 pr;
            pr.x = cvtpk(s0, s1);
            pr.y = cvtpk(s2, c3);
            *(uint2*)(hd + (quad * 4 + r) * HDS + 4 * l16) = pr;
        }

        float4v acc2[4];
        #pragma unroll
        for (int nt = 0; nt < 4; ++nt) acc2[nt] = (float4v){0.f, 0.f, 0.f, 0.f};
        #pragma unroll
        for (int ks = 0; ks < 2; ++ks) {
            short8 a2 = *(const short8*)(hd + l16 * HDS + ks * 32 + quad * 8);
            #pragma unroll
            for (int nt = 0; nt < 4; ++nt) {
                short8 bf = *(const short8*)(w2B + ((((size_t)lc * 2 + ks) * 4 + nt) << 9) + (lane << 3));
                acc2[nt] = __builtin_amdgcn_mfma_f32_16x16x32_bf16(a2, bf, acc2[nt], 0, 0, 0);
            }
        }

        // acc2[nt][r] = msg[row=quad*4+r][col=nt*16+l16]; row -> (local_i=quad, m=r)
        // z_nuc[i=base+quad][col] = sum_m msg * Y[m][col] — quad-local, no reduce.
        float p0 = 0.f, p1 = 0.f, p2 = 0.f, p3 = 0.f;
        #pragma unroll
        for (int r = 0; r < 4; ++r) {
            const float* wr = wrow + (32 + r) * WSTRIDE + l16;
            p0 += acc2[0][r] * wr[0];
            p1 += acc2[1][r] * wr[16];
            p2 += acc2[2][r] * wr[32];
            p3 += acc2[3][r] * wr[48];
        }
        unsigned short* zo = zb + (size_t)(bi + quad) * 192 + 128 + l16;
        zo[0]  = (unsigned short)cvtpk(p0, p0);
        zo[16] = (unsigned short)cvtpk(p1, p1);
        zo[32] = (unsigned short)cvtpk(p2, p2);
        zo[48] = (unsigned short)cvtpk(p3, p3);
    }
}

// ---------------- MFMA fuse: x += Z@Gcat^T + gbs; h_next = x@hW^T + hb ----------------
// Wave pairs split the output-column dim: half = wv&1 handles nt0 = half*4 .. +3
// of the x-GEMM and nt2 = half*2 .. +1 of the h-GEMM. 2 row-groups per block.
#define HXS 136   // shorts per hx row
__global__ __launch_bounds__(256) void fuse_kernel(
    const unsigned short* __restrict__ zb, const short* __restrict__ gB,
    const float* __restrict__ gbs, const float* __restrict__ X,
    const short* __restrict__ hB, const float* __restrict__ hb,
    float* __restrict__ xout, float* __restrict__ hout,
    int l, int first, int compute_h)
{
    __shared__ short hx_s[2][16 * HXS];    // 8704 B

    const int tid  = threadIdx.x;
    const int wv   = tid >> 6;
    const int lane = tid & 63;
    const int quad = lane >> 4;
    const int l16  = lane & 15;
    const int pair = wv >> 1;
    const int half = wv & 1;
    const int nt0  = half * 4;
    const int bi0  = (blockIdx.x * 2 + pair) * 16;

    // ---- Z @ Gcat^T : 6 K-steps x 4 column tiles (this wave's half) ----
    float4v ax[4];
    #pragma unroll
    for (int nt = 0; nt < 4; ++nt) ax[nt] = (float4v){0.f, 0.f, 0.f, 0.f};
    const short* gb_ = gB + (size_t)l * 48 * 512;
    const short* zrow = (const short*)zb + ((size_t)(bi0 + l16)) * 192;
    #pragma unroll
    for (int ks = 0; ks < 6; ++ks) {
        short8 az = *(const short8*)(zrow + ks * 32 + quad * 8);
        #pragma unroll
        for (int nt = 0; nt < 4; ++nt) {
            short8 bf = *(const short8*)(gb_ + (((size_t)ks * 8 + nt0 + nt) << 9) + (lane << 3));
            ax[nt] = __builtin_amdgcn_mfma_f32_16x16x32_bf16(az, bf, ax[nt], 0, 0, 0);
        }
    }

    // ---- epilogue: residual + biases, store x, pack bf16 half-rows for h-GEMM ----
    float gv[4], xb[4];
    #pragma unroll
    for (int nt = 0; nt < 4; ++nt) {
        gv[nt] = gbs[(size_t)l * D_ + (nt0 + nt) * 16 + l16];
        if (first) xb[nt] = X[(nt0 + nt) * 16 + l16];
    }
    short* hx = hx_s[pair];
    #pragma unroll
    for (int r = 0; r < 4; ++r) {
        int row = quad * 4 + r;
        size_t gi = ((size_t)(bi0 + row)) * D_ + l16;
        float xv[4];
        #pragma unroll
        for (int nt = 0; nt < 4; ++nt) {
            float xo = (first ? xb[nt] : xout[gi + (nt0 + nt) * 16]) + gv[nt] + ax[nt][r];
            xout[gi + (nt0 + nt) * 16] = xo;
            xv[nt] = xo;
        }
        if (compute_h) {
            uint2 P;
            P.x = cvtpk(xv[0], xv[1]);
            P.y = cvtpk(xv[2], xv[3]);
            *(uint2*)(hx + row * HXS + 8 * l16 + 4 * half) = P;
        }
    }
    if (!compute_h) return;
    __syncthreads();

    // ---- h_next = x @ hW^T : 4 K-steps x 2 column tiles (this wave's half) ----
    float4v ah[2];
    #pragma unroll
    for (int nt = 0; nt < 2; ++nt) ah[nt] = (float4v){0.f, 0.f, 0.f, 0.f};
    const short* hb_ = hB + (size_t)l * 16 * 512;
    #pragma unroll
    for (int ks = 0; ks < 4; ++ks) {
        short8 a = *(const short8*)(hx + l16 * HXS + ks * 32 + quad * 8);
        #pragma unroll
        for (int nt = 0; nt < 2; ++nt) {
            short8 bf = *(const short8*)(hb_ + (((size_t)ks * 4 + half * 2 + nt) << 9) + (lane << 3));
            ah[nt] = __builtin_amdgcn_mfma_f32_16x16x32_bf16(a, bf, ah[nt], 0, 0, 0);
        }
    }
    float hbv[2];
    #pragma unroll
    for (int nt = 0; nt < 2; ++nt) hbv[nt] = hb[((size_t)(l + 1)) * K_ + (half * 2 + nt) * 16 + l16];
    #pragma unroll
    for (int nt = 0; nt < 2; ++nt)
        #pragma unroll
        for (int r = 0; r < 4; ++r)
            hout[((size_t)(bi0 + quad * 4 + r)) * K_ + (half * 2 + nt) * 16 + l16] = ah[nt][r] + hbv[nt];
}

// ---------------- launch ----------------
extern "C" void kernel_launch(void* const* d_in, const int* in_sizes, int n_in,
                              void* d_out, int out_size, void* d_ws, size_t ws_size,
                              hipStream_t stream)
{
    const float* ee  = (const float*)d_in[0];
    const float* en  = (const float*)d_in[1];
    const float* X   = (const float*)d_in[2];
    const float* Y   = (const float*)d_in[3];
    const float* wW1 = (const float*)d_in[4];
    const float* wb1 = (const float*)d_in[5];
    const float* wW2 = (const float*)d_in[6];
    const float* wb2 = (const float*)d_in[7];
    const float* hW  = (const float*)d_in[8];
    const float* hb  = (const float*)d_in[9];
    const float* gW  = (const float*)d_in[10];
    const float* gb  = (const float*)d_in[11];
    float* xout = (float*)d_out;

    // workspace carve (byte offsets, all 16B-aligned)
    char* ws = (char*)d_ws;
    float*          h   = (float*)(ws);                         // 8,388,608 B
    unsigned short* zb  = (unsigned short*)(ws + 8388608);      // 12,582,912 B
    float*          h0  = (float*)(ws + 8388608 + 12582912);    // 256 B
    short*          w1B = (short*)(ws + 20971520 + 256);        // 27,648 B
    short*          w2B = w1B + (size_t)27 * 512;               // 73,728 B
    short*          gB  = w2B + (size_t)72 * 512;               // 147,456 B
    short*          hB  = gB  + (size_t)144 * 512;              // 32,768 B
    float*          gbs = (float*)(hB + (size_t)32 * 512);      // 1,536 B

    prep_kernel<<<276, 256, 0, stream>>>(wW1, wb1, wW2, wb2, gW, hW, gb,
                                         w1B, w2B, gB, hB, gbs);
    h0_kernel<<<1, 64, 0, stream>>>(X, hW, hb, h0);

    // layer 0
    edge_kernel<<<8192, 256, 0, stream>>>(ee, en, Y, w1B, wb1, w2B, h, h0, zb, 0, 0);
    fuse_kernel<<<1024, 256, 0, stream>>>(zb, gB, gbs, X, hB, hb, xout, h, 0, 1, 1);
    // layer 1
    edge_kernel<<<8192, 256, 0, stream>>>(ee, en, Y, w1B, wb1, w2B, h, h0, zb, 1, 1);
    fuse_kernel<<<1024, 256, 0, stream>>>(zb, gB, gbs, X, hB, hb, xout, h, 1, 0, 1);
    // layer 2
    edge_kernel<<<8192, 256, 0, stream>>>(ee, en, Y, w1B, wb1, w2B, h, h0, zb, 2, 1);
    fuse_kernel<<<1024, 256, 0, stream>>>(zb, gB, gbs, X, hB, hb, xout, h, 2, 0, 0);
}